// Round 3
// baseline (1317.885 us; speedup 1.0000x reference)
//
#include <hip/hip_runtime.h>
#include <hip/hip_cooperative_groups.h>

namespace cg = cooperative_groups;

// FDTD 2-step update, float32.
// v3: single persistent cooperative kernel, 4 phases with grid.sync().
// Each block owns (batch = blk&7, 8-row strip = (blk>>3)*8) for ALL phases:
// intermediates are re-read warm from the same XCD's L2/L3, and the three
// kernel-boundary drain/ramp cycles are eliminated.
// Math identical to verified v2 (fast vector path + scalar edge path).

#define KF0 (-11.0f / 12.0f)
#define KF1 (1.5f)
#define KF2 (-0.75f)
#define KF3 (1.0f / 6.0f)
#define KB0 (-1.0f / 6.0f)
#define KB1 (0.75f)
#define KB2 (-1.5f)
#define KB3 (11.0f / 12.0f)

typedef float f4 __attribute__((ext_vector_type(4)));
typedef float f2 __attribute__((ext_vector_type(2)));

__device__ __forceinline__ f4 ld4(const float* p) { f4 v; __builtin_memcpy(&v, p, 16); return v; }
__device__ __forceinline__ f2 ld2(const float* p) { f2 v; __builtin_memcpy(&v, p, 8); return v; }
__device__ __forceinline__ void st4(float* p, f4 v) { __builtin_memcpy(p, &v, 16); }

#define LOAD6(dst, p) do { f4 _a = ld4(p); f2 _b = ld2((p) + 4); \
    (dst)[0]=_a.x; (dst)[1]=_a.y; (dst)[2]=_a.z; (dst)[3]=_a.w; (dst)[4]=_b.x; (dst)[5]=_b.y; } while (0)
#define LOAD4(dst, p) do { f4 _a = ld4(p); \
    (dst)[0]=_a.x; (dst)[1]=_a.y; (dst)[2]=_a.z; (dst)[3]=_a.w; } while (0)

// ---- scalar reference paths (verified), used at domain edges ----

__device__ __forceinline__ float amper_pt(const float* __restrict__ e,
                                          const float* __restrict__ hx,
                                          const float* __restrict__ hy,
                                          int y, int x)
{
    float v = e[y * 1024 + x];
    if ((y >= 2) & (y < 1022) & (x >= 2) & (x < 1022)) {
        const float* r0 = hy + (y - 2) * 1022 + (x - 2);
        const float* r1 = r0 + 1022;
        const float* r2 = r1 + 1022;
        v += 0.5f * ((r0[0] + r0[2])
                     - (r1[0] + r1[1] + r1[2])
                     + (r2[0] + r2[1] + r2[2]));
        const float* q0 = hx + (y - 2) * 1023 + (x - 2);
        const float* q1 = q0 + 1023;
        const float* q2 = q1 + 1023;
        v -= 0.5f * ((q0[0] - q0[1] + q0[2])
                     + (-q1[1] + q1[2])
                     + (q2[0] - q2[1] + q2[2]));
    }
    bool cx = (x >= 1) & (x < 1023);
    if ((y < 1020) & cx) {
        const float* c = hy + y * 1022 + (x - 1);
        v += KF0 * c[0] + KF1 * c[1022] + KF2 * c[2044] + KF3 * c[3066];
    }
    if ((y >= 4) & cx) {
        const float* c = hy + (y - 4) * 1022 + (x - 1);
        v += KB0 * c[0] + KB1 * c[1022] + KB2 * c[2044] + KB3 * c[3066];
    }
    bool cy = (y >= 1) & (y < 1023);
    if (cy & (x < 1020)) {
        const float* r = hx + (y - 1) * 1023 + x;
        v -= KF0 * r[0] + KF1 * r[1] + KF2 * r[2] + KF3 * r[3];
    }
    if (cy & (x >= 4)) {
        const float* r = hx + (y - 1) * 1023 + (x - 4);
        v -= KB0 * r[0] + KB1 * r[1] + KB2 * r[2] + KB3 * r[3];
    }
    return v;
}

__device__ __forceinline__ float far_hx_pt(const float* __restrict__ e,
                                           const float* __restrict__ hxp,
                                           int y, int x)
{
    float v = hxp[y * 1023 + x];
    if ((x >= 1) & (x < 1022)) {
        const float* r0 = e + y * 1024 + (x - 1);
        const float* r1 = r0 + 1024;
        const float* r2 = r1 + 1024;
        v -= 0.5f * ((r0[0] - r0[1] + r0[2])
                     + (-r1[1] + r1[2])
                     + (r2[0] - r2[1] + r2[2]));
    }
    if (x < 1021) {
        const float* r = e + (y + 1) * 1024 + x;
        v -= KF0 * r[0] + KF1 * r[1] + KF2 * r[2] + KF3 * r[3];
    }
    if (x >= 2) {
        const float* r = e + (y + 1) * 1024 + (x - 2);
        v -= KB0 * r[0] + KB1 * r[1] + KB2 * r[2] + KB3 * r[3];
    }
    return v;
}

__device__ __forceinline__ float far_hy_pt(const float* __restrict__ e,
                                           const float* __restrict__ hyp,
                                           int y, int x)
{
    float v = hyp[y * 1022 + x];
    if ((y >= 1) & (y < 1022)) {
        const float* r0 = e + (y - 1) * 1024 + x;
        const float* r1 = r0 + 1024;
        const float* r2 = r1 + 1024;
        v += 0.5f * ((r0[0] + r0[2])
                     - (r1[0] + r1[1] + r1[2])
                     + (r2[0] + r2[1] + r2[2]));
    }
    if (y < 1021) {
        const float* c = e + y * 1024 + (x + 1);
        v += KF0 * c[0] + KF1 * c[1024] + KF2 * c[2048] + KF3 * c[3072];
    }
    if (y >= 2) {
        const float* c = e + (y - 2) * 1024 + (x + 1);
        v += KB0 * c[0] + KB1 * c[1024] + KB2 * c[2048] + KB3 * c[3072];
    }
    return v;
}

// ---- per-row workers (verified v2 fast paths); pointers are batch bases ----

__device__ __forceinline__ void amper_row(
    const float* __restrict__ e, const float* __restrict__ hx,
    const float* __restrict__ hy, float* __restrict__ eoB, int y, int tid)
{
    int x0 = tid << 2;
    float* eo = eoB + y * 1024;

    if ((y >= 4) & (y < 1020) & (x0 >= 4) & (x0 <= 1016)) {
        float cA[6], cB[6], cC[6];
        const float* hyr = hy + (y - 2) * 1022 + (x0 - 2);
        LOAD6(cA, hyr);
        LOAD6(cB, hyr + 1022);
        LOAD6(cC, hyr + 2044);
        float km4[4], km3[4], kp1[4], kp2[4], kp3[4];
        const float* hyc = hy + (y - 4) * 1022 + (x0 - 1);
        LOAD4(km4, hyc);
        LOAD4(km3, hyc + 1022);
        LOAD4(kp1, hyc + 5 * 1022);
        LOAD4(kp2, hyc + 6 * 1022);
        LOAD4(kp3, hyc + 7 * 1022);
        float dA[6], dC[6], e12[12];
        const float* hxr = hx + (y - 2) * 1023 + (x0 - 2);
        LOAD6(dA, hxr);
        LOAD6(dC, hxr + 2046);
        const float* hxm = hx + (y - 1) * 1023 + (x0 - 4);
        LOAD4(&e12[0], hxm);
        LOAD4(&e12[4], hxm + 4);
        LOAD4(&e12[8], hxm + 8);
        f4 ev = ld4(e + y * 1024 + x0);
        f4 o;
        #pragma unroll
        for (int j = 0; j < 4; ++j) {
            float v = ev[j];
            v += 0.5f * ((cA[j] + cA[j + 2])
                         - (cB[j] + cB[j + 1] + cB[j + 2])
                         + (cC[j] + cC[j + 1] + cC[j + 2]));
            v -= 0.5f * ((dA[j] - dA[j + 1] + dA[j + 2])
                         + (-e12[j + 3] + e12[j + 4])
                         + (dC[j] - dC[j + 1] + dC[j + 2]));
            v += KF0 * cC[j + 1] + KF1 * kp1[j] + KF2 * kp2[j] + KF3 * kp3[j];
            v += KB0 * km4[j] + KB1 * km3[j] + KB2 * cA[j + 1] + KB3 * cB[j + 1];
            v -= KF0 * e12[j + 4] + KF1 * e12[j + 5] + KF2 * e12[j + 6] + KF3 * e12[j + 7];
            v -= KB0 * e12[j] + KB1 * e12[j + 1] + KB2 * e12[j + 2] + KB3 * e12[j + 3];
            o[j] = v;
        }
        st4(eo + x0, o);
    } else {
        #pragma unroll
        for (int j = 0; j < 4; ++j)
            eo[x0 + j] = amper_pt(e, hx, hy, y, x0 + j);
    }
}

__device__ __forceinline__ void faraday_row(
    const float* __restrict__ e, const float* __restrict__ hxp,
    const float* __restrict__ hyp, float* __restrict__ hxoB,
    float* __restrict__ hyoB, int y, int tid)
{
    int x0 = tid << 2;
    bool xfast = (x0 >= 4) & (x0 <= 1016);

    if (y < 1022) {
        float* hxo = hxoB + y * 1023;
        if (xfast) {
            float gA[6], gC[6], h9[9];
            const float* er = e + y * 1024 + (x0 - 1);
            LOAD6(gA, er);
            LOAD6(gC, er + 2048);
            const float* em = e + (y + 1) * 1024 + (x0 - 2);
            LOAD4(&h9[0], em);
            LOAD4(&h9[4], em + 4);
            h9[8] = em[8];
            f4 hv = ld4(hxp + y * 1023 + x0);
            f4 o;
            #pragma unroll
            for (int j = 0; j < 4; ++j) {
                float v = hv[j];
                v -= 0.5f * ((gA[j] - gA[j + 1] + gA[j + 2])
                             + (-h9[j + 2] + h9[j + 3])
                             + (gC[j] - gC[j + 1] + gC[j + 2]));
                v -= KF0 * h9[j + 2] + KF1 * h9[j + 3] + KF2 * h9[j + 4] + KF3 * h9[j + 5];
                v -= KB0 * h9[j] + KB1 * h9[j + 1] + KB2 * h9[j + 2] + KB3 * h9[j + 3];
                o[j] = v;
            }
            st4(hxo + x0, o);
        } else {
            for (int j = 0; j < 4; ++j) {
                int x = x0 + j;
                if (x < 1023) hxo[x] = far_hx_pt(e, hxp, y, x);
            }
        }
    }

    {
        float* hyo = hyoB + y * 1022;
        if (xfast & (y >= 2) & (y <= 1020)) {
            float mA[6], mB[6], mC[6], nA[4], nD[4], nE[4];
            const float* er = e + (y - 1) * 1024 + x0;
            LOAD6(mA, er);
            LOAD6(mB, er + 1024);
            LOAD6(mC, er + 2048);
            const float* en = e + (y - 2) * 1024 + (x0 + 1);
            LOAD4(nA, en);
            LOAD4(nD, en + 4 * 1024);
            LOAD4(nE, en + 5 * 1024);
            f4 hv = ld4(hyp + y * 1022 + x0);
            f4 o;
            #pragma unroll
            for (int j = 0; j < 4; ++j) {
                float v = hv[j];
                v += 0.5f * ((mA[j] + mA[j + 2])
                             - (mB[j] + mB[j + 1] + mB[j + 2])
                             + (mC[j] + mC[j + 1] + mC[j + 2]));
                v += KF0 * mB[j + 1] + KF1 * mC[j + 1] + KF2 * nD[j] + KF3 * nE[j];
                v += KB0 * nA[j] + KB1 * mA[j + 1] + KB2 * mB[j + 1] + KB3 * mC[j + 1];
                o[j] = v;
            }
            st4(hyo + x0, o);
        } else {
            for (int j = 0; j < 4; ++j) {
                int x = x0 + j;
                if (x < 1022) hyo[x] = far_hy_pt(e, hyp, y, x);
            }
        }
    }
}

// ---- fused cooperative kernel: 1024 blocks (4/CU), 4 phases ----

__global__ __launch_bounds__(256, 4) void fdtd_fused(
    const float* __restrict__ E, const float* __restrict__ Hx,
    const float* __restrict__ Hy, float* __restrict__ Eo,
    float* __restrict__ Hxo, float* __restrict__ Hyo)
{
    int tid = threadIdx.x;
    int blk = blockIdx.x;          // 0..1023
    int b = blk & 7;               // batch == XCD (blk%8)
    int ys = (blk >> 3) << 3;      // 8-row strip start: 0..1016

    const float* e  = E  + (size_t)b * (1024 * 1024);
    const float* hx = Hx + (size_t)b * (1022 * 1023);
    const float* hy = Hy + (size_t)b * (1023 * 1022);
    float* eo1  = Eo  + (size_t)b * (2 * 1024 * 1024);
    float* eo2  = eo1 + 1024 * 1024;
    float* hxo1 = Hxo + (size_t)b * (2 * 1045506);
    float* hxo2 = hxo1 + 1045506;
    float* hyo1 = Hyo + (size_t)b * (2 * 1045506);
    float* hyo2 = hyo1 + 1045506;

    cg::grid_group grid = cg::this_grid();

    #pragma unroll 1
    for (int i = 0; i < 8; ++i)
        amper_row(e, hx, hy, eo1, ys + i, tid);
    __threadfence();
    grid.sync();

    #pragma unroll 1
    for (int i = 0; i < 8; ++i) {
        int y = ys + i;
        if (y < 1023) faraday_row(eo1, hx, hy, hxo1, hyo1, y, tid);
    }
    __threadfence();
    grid.sync();

    #pragma unroll 1
    for (int i = 0; i < 8; ++i)
        amper_row(eo1, hxo1, hyo1, eo2, ys + i, tid);
    __threadfence();
    grid.sync();

    #pragma unroll 1
    for (int i = 0; i < 8; ++i) {
        int y = ys + i;
        if (y < 1023) faraday_row(eo2, hxo1, hyo1, hxo2, hyo2, y, tid);
    }
}

// ---- fallback: 4 separate launches (same device code) ----

__global__ __launch_bounds__(256) void amper_k(
    const float* __restrict__ E, int sEb,
    const float* __restrict__ Hx, int sHxb,
    const float* __restrict__ Hy, int sHyb,
    float* __restrict__ Eo, int sEob)
{
    int lin = blockIdx.y + (blockIdx.z << 10);
    int b = lin & 7;
    int y = lin >> 3;
    amper_row(E + (size_t)b * sEb, Hx + (size_t)b * sHxb,
              Hy + (size_t)b * sHyb, Eo + (size_t)b * sEob, y, threadIdx.x);
}

__global__ __launch_bounds__(256) void faraday_k(
    const float* __restrict__ E, int sEb,
    const float* __restrict__ Hx, int sHxb,
    const float* __restrict__ Hy, int sHyb,
    float* __restrict__ Hxo, int sHxob,
    float* __restrict__ Hyo, int sHyob)
{
    int lin = blockIdx.y + 1023 * blockIdx.z;
    int b = lin & 7;
    int y = lin >> 3;
    faraday_row(E + (size_t)b * sEb, Hx + (size_t)b * sHxb,
                Hy + (size_t)b * sHyb, Hxo + (size_t)b * sHxob,
                Hyo + (size_t)b * sHyob, y, threadIdx.x);
}

extern "C" void kernel_launch(void* const* d_in, const int* in_sizes, int n_in,
                              void* d_out, int out_size, void* d_ws, size_t ws_size,
                              hipStream_t stream)
{
    const float* E  = (const float*)d_in[0];
    const float* Hx = (const float*)d_in[1];
    const float* Hy = (const float*)d_in[2];

    float* out = (float*)d_out;
    float* Eo  = out;                      // 8 * 2048 * 1024
    float* Hxo = out + 16777216;           // 8 * 2044 * 1023
    float* Hyo = Hxo + 16728096;           // 8 * 2046 * 1022

    void* kargs[6] = { (void*)&E, (void*)&Hx, (void*)&Hy,
                       (void*)&Eo, (void*)&Hxo, (void*)&Hyo };
    hipError_t err = hipLaunchCooperativeKernel(
        reinterpret_cast<void*>(fdtd_fused),
        dim3(1024, 1, 1), dim3(256, 1, 1), kargs, 0, stream);

    if (err != hipSuccess) {
        // fallback: 4-kernel sequence (v2 behavior)
        const int sE = 1024 * 1024;
        const int sHx = 1022 * 1023;
        const int sHy = 1023 * 1022;
        const int sEo = 2 * 1024 * 1024;
        const int sHo = 2 * 1045506;
        dim3 blk(256, 1, 1);
        dim3 gA(1, 1024, 8);
        dim3 gF(1, 1023, 8);
        amper_k<<<gA, blk, 0, stream>>>(E, sE, Hx, sHx, Hy, sHy, Eo, sEo);
        faraday_k<<<gF, blk, 0, stream>>>(Eo, sEo, Hx, sHx, Hy, sHy,
                                          Hxo, sHo, Hyo, sHo);
        amper_k<<<gA, blk, 0, stream>>>(Eo, sEo, Hxo, sHo, Hyo, sHo,
                                        Eo + 1024 * 1024, sEo);
        faraday_k<<<gF, blk, 0, stream>>>(Eo + 1024 * 1024, sEo, Hxo, sHo, Hyo, sHo,
                                          Hxo + 1045506, sHo, Hyo + 1045506, sHo);
    }
}

// Round 4
// 416.320 us; speedup vs baseline: 3.1656x; 3.1656x over previous
//
#include <hip/hip_runtime.h>

// FDTD 2-step update, float32.
// Fields: E (B,1024,1024), Hx (B,1022,1023), Hy (B,1023,1022), B=8.
// v4: 4 plain launches (no cooperative). Each kernel is LDS-staged:
//   block = (xt in {0,1}, batch b, 4-row strip y0=4s), 256 threads.
//   Stage input window once with aligned f4 loads -> barrier -> compute
//   4x512 outputs from LDS (verified v2 math; scalar guarded path at edges).

#define KF0 (-11.0f / 12.0f)
#define KF1 (1.5f)
#define KF2 (-0.75f)
#define KF3 (1.0f / 6.0f)
#define KB0 (-1.0f / 6.0f)
#define KB1 (0.75f)
#define KB2 (-1.5f)
#define KB3 (11.0f / 12.0f)

typedef float f4 __attribute__((ext_vector_type(4)));
typedef float f2 __attribute__((ext_vector_type(2)));

__device__ __forceinline__ f4 ld4(const float* p) { f4 v; __builtin_memcpy(&v, p, 16); return v; }
__device__ __forceinline__ void st4(float* p, f4 v) { __builtin_memcpy(p, &v, 16); }

#define LOAD6(dst, p) do { __builtin_memcpy(dst, p, 24); } while (0)
#define LOAD4(dst, p) do { __builtin_memcpy(dst, p, 16); } while (0)

// ---------------- amper: E_n = E + S1 - S2 over (1024,1024) ----------------
// LDS windows: hyS rows [y0-4, y0+6] (11), hxS rows [y0-2, y0+3] (6),
// cols [xb-4, xb+516) (520, pitch 520).

#define HYP 520
#define HYS_AT(r, c) hyS[((r) - y0 + 4) * HYP + ((c) - xb + 4)]
#define HXS_AT(r, c) hxS[((r) - y0 + 2) * HYP + ((c) - xb + 4)]

__device__ __forceinline__ float amper_pt_lds(
    const float* __restrict__ e, const float* hxS, const float* hyS,
    int y0, int xb, int y, int x)
{
    float v = e[y * 1024 + x];
    if ((y >= 2) & (y < 1022) & (x >= 2) & (x < 1022)) {
        v += 0.5f * ((HYS_AT(y-2, x-2) + HYS_AT(y-2, x))
                     - (HYS_AT(y-1, x-2) + HYS_AT(y-1, x-1) + HYS_AT(y-1, x))
                     + (HYS_AT(y, x-2) + HYS_AT(y, x-1) + HYS_AT(y, x)));
        v -= 0.5f * ((HXS_AT(y-2, x-2) - HXS_AT(y-2, x-1) + HXS_AT(y-2, x))
                     + (-HXS_AT(y-1, x-1) + HXS_AT(y-1, x))
                     + (HXS_AT(y, x-2) - HXS_AT(y, x-1) + HXS_AT(y, x)));
    }
    bool cx = (x >= 1) & (x < 1023);
    if ((y < 1020) & cx) {
        v += KF0 * HYS_AT(y, x-1) + KF1 * HYS_AT(y+1, x-1)
           + KF2 * HYS_AT(y+2, x-1) + KF3 * HYS_AT(y+3, x-1);
    }
    if ((y >= 4) & cx) {
        v += KB0 * HYS_AT(y-4, x-1) + KB1 * HYS_AT(y-3, x-1)
           + KB2 * HYS_AT(y-2, x-1) + KB3 * HYS_AT(y-1, x-1);
    }
    bool cy = (y >= 1) & (y < 1023);
    if (cy & (x < 1020)) {
        v -= KF0 * HXS_AT(y-1, x) + KF1 * HXS_AT(y-1, x+1)
           + KF2 * HXS_AT(y-1, x+2) + KF3 * HXS_AT(y-1, x+3);
    }
    if (cy & (x >= 4)) {
        v -= KB0 * HXS_AT(y-1, x-4) + KB1 * HXS_AT(y-1, x-3)
           + KB2 * HXS_AT(y-1, x-2) + KB3 * HXS_AT(y-1, x-1);
    }
    return v;
}

__global__ __launch_bounds__(256) void amper_k(
    const float* __restrict__ E, int sEb,
    const float* __restrict__ Hx, int sHxb,
    const float* __restrict__ Hy, int sHyb,
    float* __restrict__ Eo, int sEob)
{
    int xt = blockIdx.x;           // 0..1
    int b  = blockIdx.y;           // 0..7
    int s  = blockIdx.z;           // 0..255
    int y0 = s << 2;
    int xb = xt << 9;

    const float* e  = E  + (size_t)b * sEb;
    const float* hx = Hx + (size_t)b * sHxb;
    const float* hy = Hy + (size_t)b * sHyb;
    float* eo = Eo + (size_t)b * sEob;

    __shared__ float hyS[11 * HYP];
    __shared__ float hxS[6 * HYP];

    int tid = threadIdx.x;

    // stage Hy rows y0-4..y0+6, cols xb-4..xb+515 (130 f4/row)
    for (int idx = tid; idx < 11 * 130; idx += 256) {
        int i = idx / 130, j = idx - i * 130;
        int gr = y0 - 4 + i;
        int gc = xb - 4 + (j << 2);
        f4 v = {0.f, 0.f, 0.f, 0.f};
        if ((unsigned)gr < 1023u) {
            const float* p = hy + gr * 1022;
            if ((gc >= 0) & (gc + 3 < 1022)) v = ld4(p + gc);
            else {
                #pragma unroll
                for (int k = 0; k < 4; ++k) {
                    int c = gc + k;
                    if ((unsigned)c < 1022u) v[k] = p[c];
                }
            }
        }
        st4(&hyS[i * HYP + (j << 2)], v);
    }
    // stage Hx rows y0-2..y0+3
    for (int idx = tid; idx < 6 * 130; idx += 256) {
        int i = idx / 130, j = idx - i * 130;
        int gr = y0 - 2 + i;
        int gc = xb - 4 + (j << 2);
        f4 v = {0.f, 0.f, 0.f, 0.f};
        if ((unsigned)gr < 1022u) {
            const float* p = hx + gr * 1023;
            if ((gc >= 0) & (gc + 3 < 1023)) v = ld4(p + gc);
            else {
                #pragma unroll
                for (int k = 0; k < 4; ++k) {
                    int c = gc + k;
                    if ((unsigned)c < 1023u) v[k] = p[c];
                }
            }
        }
        st4(&hxS[i * HYP + (j << 2)], v);
    }
    __syncthreads();

    int tx = tid & 127, ty = tid >> 7;
    int c0 = xb + (tx << 2);

    #pragma unroll
    for (int rr = 0; rr < 2; ++rr) {
        int y = y0 + (ty << 1) + rr;
        float* eorow = eo + y * 1024;
        if ((y >= 4) & (y < 1020) & (c0 >= 4) & (c0 <= 1016)) {
            // v2 fast path, sources in LDS
            const float* hyr = &hyS[(y - y0 + 2) * HYP + (c0 - xb + 2)];
            float cA[6], cB[6], cC[6];
            LOAD6(cA, hyr);
            LOAD6(cB, hyr + HYP);
            LOAD6(cC, hyr + 2 * HYP);
            const float* hyc = &hyS[(y - y0) * HYP + (c0 - xb + 3)];
            float km4[4], km3[4], kp1[4], kp2[4], kp3[4];
            LOAD4(km4, hyc);
            LOAD4(km3, hyc + HYP);
            LOAD4(kp1, hyc + 5 * HYP);
            LOAD4(kp2, hyc + 6 * HYP);
            LOAD4(kp3, hyc + 7 * HYP);
            const float* hxr = &hxS[(y - y0) * HYP + (c0 - xb + 2)];
            float dA[6], dC[6], e12[12];
            LOAD6(dA, hxr);
            LOAD6(dC, hxr + 2 * HYP);
            const float* hxm = &hxS[(y - y0 + 1) * HYP + (c0 - xb)];
            LOAD4(&e12[0], hxm);
            LOAD4(&e12[4], hxm + 4);
            LOAD4(&e12[8], hxm + 8);
            f4 ev = ld4(e + y * 1024 + c0);
            f4 o;
            #pragma unroll
            for (int j = 0; j < 4; ++j) {
                float v = ev[j];
                v += 0.5f * ((cA[j] + cA[j + 2])
                             - (cB[j] + cB[j + 1] + cB[j + 2])
                             + (cC[j] + cC[j + 1] + cC[j + 2]));
                v -= 0.5f * ((dA[j] - dA[j + 1] + dA[j + 2])
                             + (-e12[j + 3] + e12[j + 4])
                             + (dC[j] - dC[j + 1] + dC[j + 2]));
                v += KF0 * cC[j + 1] + KF1 * kp1[j] + KF2 * kp2[j] + KF3 * kp3[j];
                v += KB0 * km4[j] + KB1 * km3[j] + KB2 * cA[j + 1] + KB3 * cB[j + 1];
                v -= KF0 * e12[j + 4] + KF1 * e12[j + 5] + KF2 * e12[j + 6] + KF3 * e12[j + 7];
                v -= KB0 * e12[j] + KB1 * e12[j + 1] + KB2 * e12[j + 2] + KB3 * e12[j + 3];
                o[j] = v;
            }
            st4(eorow + c0, o);
        } else {
            #pragma unroll
            for (int j = 0; j < 4; ++j)
                eorow[c0 + j] = amper_pt_lds(e, hxS, hyS, y0, xb, y, c0 + j);
        }
    }
}

// ---------------- faraday: Hx_n (1022,1023), Hy_n (1023,1022) ----------------
// LDS window: eS rows [y0-2, y0+6] (9), cols [xb-4, xb+520) (524, pitch 524).

#define EP 524
#define ES_AT(r, c) eS[((r) - y0 + 2) * EP + ((c) - xb + 4)]

__device__ __forceinline__ float far_hx_pt_lds(
    const float* eS, const float* __restrict__ hxp,
    int y0, int xb, int y, int x)
{
    float v = hxp[y * 1023 + x];
    if ((x >= 1) & (x < 1022)) {
        v -= 0.5f * ((ES_AT(y, x-1) - ES_AT(y, x) + ES_AT(y, x+1))
                     + (-ES_AT(y+1, x) + ES_AT(y+1, x+1))
                     + (ES_AT(y+2, x-1) - ES_AT(y+2, x) + ES_AT(y+2, x+1)));
    }
    if (x < 1021) {
        v -= KF0 * ES_AT(y+1, x) + KF1 * ES_AT(y+1, x+1)
           + KF2 * ES_AT(y+1, x+2) + KF3 * ES_AT(y+1, x+3);
    }
    if (x >= 2) {
        v -= KB0 * ES_AT(y+1, x-2) + KB1 * ES_AT(y+1, x-1)
           + KB2 * ES_AT(y+1, x) + KB3 * ES_AT(y+1, x+1);
    }
    return v;
}

__device__ __forceinline__ float far_hy_pt_lds(
    const float* eS, const float* __restrict__ hyp,
    int y0, int xb, int y, int x)
{
    float v = hyp[y * 1022 + x];
    if ((y >= 1) & (y < 1022)) {
        v += 0.5f * ((ES_AT(y-1, x) + ES_AT(y-1, x+2))
                     - (ES_AT(y, x) + ES_AT(y, x+1) + ES_AT(y, x+2))
                     + (ES_AT(y+1, x) + ES_AT(y+1, x+1) + ES_AT(y+1, x+2)));
    }
    if (y < 1021) {
        v += KF0 * ES_AT(y, x+1) + KF1 * ES_AT(y+1, x+1)
           + KF2 * ES_AT(y+2, x+1) + KF3 * ES_AT(y+3, x+1);
    }
    if (y >= 2) {
        v += KB0 * ES_AT(y-2, x+1) + KB1 * ES_AT(y-1, x+1)
           + KB2 * ES_AT(y, x+1) + KB3 * ES_AT(y+1, x+1);
    }
    return v;
}

__global__ __launch_bounds__(256) void faraday_k(
    const float* __restrict__ E, int sEb,
    const float* __restrict__ Hx, int sHxb,
    const float* __restrict__ Hy, int sHyb,
    float* __restrict__ Hxo, int sHxob,
    float* __restrict__ Hyo, int sHyob)
{
    int xt = blockIdx.x;           // 0..1
    int b  = blockIdx.y;           // 0..7
    int s  = blockIdx.z;           // 0..255
    int y0 = s << 2;
    int xb = xt << 9;

    const float* e   = E  + (size_t)b * sEb;
    const float* hxp = Hx + (size_t)b * sHxb;
    const float* hyp = Hy + (size_t)b * sHyb;
    float* hxo = Hxo + (size_t)b * sHxob;
    float* hyo = Hyo + (size_t)b * sHyob;

    __shared__ float eS[9 * EP];

    int tid = threadIdx.x;

    // stage E rows y0-2..y0+6, cols xb-4..xb+519 (131 f4/row)
    for (int idx = tid; idx < 9 * 131; idx += 256) {
        int i = idx / 131, j = idx - i * 131;
        int gr = y0 - 2 + i;
        int gc = xb - 4 + (j << 2);
        f4 v = {0.f, 0.f, 0.f, 0.f};
        if ((unsigned)gr < 1024u) {
            const float* p = e + gr * 1024;
            if ((gc >= 0) & (gc + 3 < 1024)) v = ld4(p + gc);
            else {
                #pragma unroll
                for (int k = 0; k < 4; ++k) {
                    int c = gc + k;
                    if ((unsigned)c < 1024u) v[k] = p[c];
                }
            }
        }
        st4(&eS[i * EP + (j << 2)], v);
    }
    __syncthreads();

    int tx = tid & 127, ty = tid >> 7;
    int c0 = xb + (tx << 2);
    bool cfast = (c0 >= 4) & (c0 <= 1016);

    #pragma unroll
    for (int rr = 0; rr < 2; ++rr) {
        int y = y0 + (ty << 1) + rr;

        // Hx part: y in [0,1022), x in [0,1023)
        if (y < 1022) {
            float* hxorow = hxo + y * 1023;
            if (cfast) {
                const float* er = &eS[(y - y0 + 2) * EP + (c0 - xb + 3)];
                float gA[6], gC[6], h9[9];
                LOAD6(gA, er);
                LOAD6(gC, er + 2 * EP);
                const float* em = &eS[(y - y0 + 3) * EP + (c0 - xb + 2)];
                LOAD4(&h9[0], em);
                LOAD4(&h9[4], em + 4);
                h9[8] = em[8];
                f4 hv = ld4(hxp + y * 1023 + c0);
                f4 o;
                #pragma unroll
                for (int j = 0; j < 4; ++j) {
                    float v = hv[j];
                    v -= 0.5f * ((gA[j] - gA[j + 1] + gA[j + 2])
                                 + (-h9[j + 2] + h9[j + 3])
                                 + (gC[j] - gC[j + 1] + gC[j + 2]));
                    v -= KF0 * h9[j + 2] + KF1 * h9[j + 3] + KF2 * h9[j + 4] + KF3 * h9[j + 5];
                    v -= KB0 * h9[j] + KB1 * h9[j + 1] + KB2 * h9[j + 2] + KB3 * h9[j + 3];
                    o[j] = v;
                }
                st4(hxorow + c0, o);
            } else {
                #pragma unroll
                for (int j = 0; j < 4; ++j) {
                    int x = c0 + j;
                    if (x < 1023) hxorow[x] = far_hx_pt_lds(eS, hxp, y0, xb, y, x);
                }
            }
        }

        // Hy part: y in [0,1023), x in [0,1022)
        if (y < 1023) {
            float* hyorow = hyo + y * 1022;
            if (cfast & (y >= 2) & (y <= 1020)) {
                const float* er = &eS[(y - y0 + 1) * EP + (c0 - xb + 4)];
                float mA[6], mB[6], mC[6], nA[4], nD[4], nE[4];
                LOAD6(mA, er);
                LOAD6(mB, er + EP);
                LOAD6(mC, er + 2 * EP);
                const float* en = &eS[(y - y0) * EP + (c0 - xb + 5)];
                LOAD4(nA, en);
                LOAD4(nD, en + 4 * EP);
                LOAD4(nE, en + 5 * EP);
                f4 hv = ld4(hyp + y * 1022 + c0);
                f4 o;
                #pragma unroll
                for (int j = 0; j < 4; ++j) {
                    float v = hv[j];
                    v += 0.5f * ((mA[j] + mA[j + 2])
                                 - (mB[j] + mB[j + 1] + mB[j + 2])
                                 + (mC[j] + mC[j + 1] + mC[j + 2]));
                    v += KF0 * mB[j + 1] + KF1 * mC[j + 1] + KF2 * nD[j] + KF3 * nE[j];
                    v += KB0 * nA[j] + KB1 * mA[j + 1] + KB2 * mB[j + 1] + KB3 * mC[j + 1];
                    o[j] = v;
                }
                st4(hyorow + c0, o);
            } else {
                #pragma unroll
                for (int j = 0; j < 4; ++j) {
                    int x = c0 + j;
                    if (x < 1022) hyorow[x] = far_hy_pt_lds(eS, hyp, y0, xb, y, x);
                }
            }
        }
    }
}

extern "C" void kernel_launch(void* const* d_in, const int* in_sizes, int n_in,
                              void* d_out, int out_size, void* d_ws, size_t ws_size,
                              hipStream_t stream)
{
    const float* E  = (const float*)d_in[0];
    const float* Hx = (const float*)d_in[1];
    const float* Hy = (const float*)d_in[2];

    float* out = (float*)d_out;
    float* Eo  = out;                      // 8 * 2048 * 1024
    float* Hxo = out + 16777216;           // 8 * 2044 * 1023
    float* Hyo = Hxo + 16728096;           // 8 * 2046 * 1022

    const int sE = 1024 * 1024;
    const int sHx = 1022 * 1023;
    const int sHy = 1023 * 1022;
    const int sEo = 2 * 1024 * 1024;
    const int sHo = 2 * 1045506;

    dim3 blk(256, 1, 1);
    dim3 g(2, 8, 256);   // (x-half, batch, 4-row strip); lin%8 keeps batch/XCD streams

    // step 1: E_n = amper(E, Hx, Hy)
    amper_k<<<g, blk, 0, stream>>>(E, sE, Hx, sHx, Hy, sHy, Eo, sEo);
    // step 2: Hx_n, Hy_n = faraday(E_n, Hx, Hy)
    faraday_k<<<g, blk, 0, stream>>>(Eo, sEo, Hx, sHx, Hy, sHy,
                                     Hxo, sHo, Hyo, sHo);
    // step 3: E_m = amper(E_n, Hx_n, Hy_n)
    amper_k<<<g, blk, 0, stream>>>(Eo, sEo, Hxo, sHo, Hyo, sHo,
                                   Eo + 1024 * 1024, sEo);
    // step 4: Hx_m, Hy_m = faraday(E_m, Hx_n, Hy_n)
    faraday_k<<<g, blk, 0, stream>>>(Eo + 1024 * 1024, sEo, Hxo, sHo, Hyo, sHo,
                                     Hxo + 1045506, sHo, Hyo + 1045506, sHo);
}